// Round 6
// baseline (297.252 us; speedup 1.0000x reference)
//
#include <hip/hip_runtime.h>
#include <hip/hip_bf16.h>
#include <cstdint>

constexpr int N_NODES = 50000;
constexpr int N_EDGES = 800000;
constexpr int F_IN    = 128;
constexpr int F_HID   = 256;
constexpr int N_COLS  = 256;
constexpr int M_PAD   = 50048;   // 782 * 64
constexpr int NB_SCAN = (N_NODES + 255) / 256;   // 196 blocks

typedef unsigned short u16;
typedef u16   ushort4v __attribute__((ext_vector_type(4)));
typedef u16   ushort8v __attribute__((ext_vector_type(8)));
typedef __bf16 bf16x8  __attribute__((ext_vector_type(8)));
typedef float  f32x4   __attribute__((ext_vector_type(4)));

__device__ __forceinline__ float bf2f(u16 u) {
    return __uint_as_float(((uint32_t)u) << 16);
}
__device__ __forceinline__ u16 f2bf(float f) {
    uint32_t u = __float_as_uint(f);
    uint32_t r = u + 0x7FFFu + ((u >> 16) & 1u);   // RNE
    return (u16)(r >> 16);
}

// async global->LDS, 16B per lane. LDS dest is wave-uniform base; HW adds lane*16.
__device__ __forceinline__ void gll16(const void* g, void* l) {
    __builtin_amdgcn_global_load_lds(
        (const __attribute__((address_space(1))) uint32_t*)(uintptr_t)g,
        (__attribute__((address_space(3))) uint32_t*)(uintptr_t)l,
        16, 0, 0);
}

// ---------------------------------------------------------------------------
// CSR build
// ---------------------------------------------------------------------------
__global__ void deg_kernel(const int* __restrict__ dst, int* __restrict__ deg) {
    int e = blockIdx.x * blockDim.x + threadIdx.x;
    if (e < N_EDGES) atomicAdd(&deg[dst[e]], 1);
}

__global__ __launch_bounds__(256) void block_sum_kernel(const int* __restrict__ deg,
                                                        int* __restrict__ part) {
    const int n = blockIdx.x * 256 + threadIdx.x;
    int v = (n < N_NODES) ? deg[n] : 0;
    #pragma unroll
    for (int o = 32; o > 0; o >>= 1) v += __shfl_down(v, o, 64);
    __shared__ int s[4];
    if ((threadIdx.x & 63) == 0) s[threadIdx.x >> 6] = v;
    __syncthreads();
    if (threadIdx.x == 0) part[blockIdx.x] = s[0] + s[1] + s[2] + s[3];
}

__global__ __launch_bounds__(256) void part_scan_kernel(int* __restrict__ part,
                                                        int* __restrict__ row_ptr) {
    __shared__ int s[256];
    const int tid = threadIdx.x;
    int v = (tid < NB_SCAN) ? part[tid] : 0;
    s[tid] = v;
    __syncthreads();
    #pragma unroll
    for (int o = 1; o < 256; o <<= 1) {
        int t = 0;
        if (tid >= o) t = s[tid - o];
        __syncthreads();
        s[tid] += t;
        __syncthreads();
    }
    if (tid < NB_SCAN) part[tid] = s[tid] - v;
    if (tid == 255) row_ptr[N_NODES] = s[255];
}

__global__ __launch_bounds__(256) void row_ptr_kernel(const int* __restrict__ deg,
                                                      const int* __restrict__ part,
                                                      int* __restrict__ row_ptr,
                                                      float* __restrict__ inv_deg) {
    __shared__ int s[256];
    const int tid = threadIdx.x;
    const int n = blockIdx.x * 256 + tid;
    const int d = (n < N_NODES) ? deg[n] : 0;
    s[tid] = d;
    __syncthreads();
    #pragma unroll
    for (int o = 1; o < 256; o <<= 1) {
        int t = 0;
        if (tid >= o) t = s[tid - o];
        __syncthreads();
        s[tid] += t;
        __syncthreads();
    }
    if (n < N_NODES) {
        row_ptr[n] = part[blockIdx.x] + s[tid] - d;
        inv_deg[n] = (d > 0) ? (1.0f / (float)d) : 0.0f;
    }
}

__global__ void fill_kernel(const int* __restrict__ src, const int* __restrict__ dst,
                            const int* __restrict__ row_ptr, int* __restrict__ cursor,
                            int* __restrict__ col) {
    int e = blockIdx.x * blockDim.x + threadIdx.x;
    if (e < N_EDGES) {
        int d = dst[e];
        int pos = atomicAdd(&cursor[d], 1);
        col[row_ptr[d] + pos] = src[e];
    }
}

// ---------------------------------------------------------------------------
// fp32 -> bf16 convert
// ---------------------------------------------------------------------------
__global__ __launch_bounds__(256) void f2bf_kernel(const float* __restrict__ in,
                                                   u16* __restrict__ out, int n4) {
    int i = blockIdx.x * blockDim.x + threadIdx.x;
    if (i < n4) {
        float4 v = *reinterpret_cast<const float4*>(&in[(size_t)i * 4]);
        ushort4v o;
        o.x = f2bf(v.x); o.y = f2bf(v.y); o.z = f2bf(v.z); o.w = f2bf(v.w);
        *reinterpret_cast<ushort4v*>(&out[(size_t)i * 4]) = o;
    }
}

// W [K][256] fp32 -> Wt [256][K] bf16
template <int K>
__global__ __launch_bounds__(256) void wtrans(const float* __restrict__ W,
                                              u16* __restrict__ Wt) {
    const int n = blockIdx.x;
    for (int k = threadIdx.x; k < K; k += 256)
        Wt[(size_t)n * K + k] = f2bf(W[(size_t)k * N_COLS + n]);
}

// ---------------------------------------------------------------------------
// Fused [aggregate 64 rows -> LDS] + [GEMM  relu([H | agg] @ W + b)].
// H: [M_PAD][FIN] bf16 (both the A1 operand rows and the gather table).
// Bt: [256][2*FIN] bf16 (W^T). Per block: 64 output rows x 256 cols.
// Phase 1: mean-aggregate rows m0..m0+63 from H via CSR into aggT (swizzled).
// Phase 2: m97-style MFMA GEMM; A2 fragments read straight from aggT.
// LDS: aggT 64*FIN*2B + As 4KB + Bs 16KB  (36KB / 52KB -> 4 / 3 blocks/CU).
// ---------------------------------------------------------------------------
template <int FIN, bool OUT_BF16>
__global__ __launch_bounds__(256) void fused_agg_gemm(const u16* __restrict__ H,
                                                      const int* __restrict__ rp,
                                                      const int* __restrict__ colv,
                                                      const float* __restrict__ invd,
                                                      const u16* __restrict__ Bt,
                                                      const float* __restrict__ bias,
                                                      void* __restrict__ Cout, int M) {
    constexpr int K   = 2 * FIN;
    constexpr int LPN = FIN / 8;        // lanes per node row
    constexpr int NPB = 256 / LPN;      // node rows aggregated concurrently
    __shared__ u16 aggT[64 * FIN];      // XOR-swizzled row-major [64][FIN]
    __shared__ u16 As[64 * 32];
    __shared__ u16 Bs[256 * 32];

    const int t  = threadIdx.x;
    const int m0 = blockIdx.x * 64;

    // ---------------- Phase 1: aggregation into LDS ----------------
    {
        const int slot = t / LPN;
        const int ln   = t % LPN;
        #pragma unroll 1
        for (int p = 0; p < 64 / NPB; ++p) {
            const int r = p * NPB + slot;     // tile row 0..63
            const int n = m0 + r;
            float acc0[8] = {}, acc1[8] = {};
            float s = 0.f;
            if (n < N_NODES) {
                const int beg = rp[n], end = rp[n + 1];
                s = invd[n];
                int e = beg;
                for (; e + 3 < end; e += 4) {
                    int nb0 = colv[e];
                    int nb1 = colv[e + 1];
                    int nb2 = colv[e + 2];
                    int nb3 = colv[e + 3];
                    ushort8v v0 = *reinterpret_cast<const ushort8v*>(&H[(size_t)nb0 * FIN + ln * 8]);
                    ushort8v v1 = *reinterpret_cast<const ushort8v*>(&H[(size_t)nb1 * FIN + ln * 8]);
                    ushort8v v2 = *reinterpret_cast<const ushort8v*>(&H[(size_t)nb2 * FIN + ln * 8]);
                    ushort8v v3 = *reinterpret_cast<const ushort8v*>(&H[(size_t)nb3 * FIN + ln * 8]);
                    #pragma unroll
                    for (int j = 0; j < 8; ++j) acc0[j] += bf2f(v0[j]);
                    #pragma unroll
                    for (int j = 0; j < 8; ++j) acc1[j] += bf2f(v1[j]);
                    #pragma unroll
                    for (int j = 0; j < 8; ++j) acc0[j] += bf2f(v2[j]);
                    #pragma unroll
                    for (int j = 0; j < 8; ++j) acc1[j] += bf2f(v3[j]);
                }
                if (e + 1 < end) {
                    int nb0 = colv[e];
                    int nb1 = colv[e + 1];
                    ushort8v v0 = *reinterpret_cast<const ushort8v*>(&H[(size_t)nb0 * FIN + ln * 8]);
                    ushort8v v1 = *reinterpret_cast<const ushort8v*>(&H[(size_t)nb1 * FIN + ln * 8]);
                    #pragma unroll
                    for (int j = 0; j < 8; ++j) acc0[j] += bf2f(v0[j]);
                    #pragma unroll
                    for (int j = 0; j < 8; ++j) acc1[j] += bf2f(v1[j]);
                    e += 2;
                }
                if (e < end) {
                    ushort8v v = *reinterpret_cast<const ushort8v*>(&H[(size_t)colv[e] * FIN + ln * 8]);
                    #pragma unroll
                    for (int j = 0; j < 8; ++j) acc0[j] += bf2f(v[j]);
                }
            }
            ushort8v o;
            #pragma unroll
            for (int j = 0; j < 8; ++j) o[j] = f2bf((acc0[j] + acc1[j]) * s);
            // swizzled 16B store: byte ^= (row&7)<<4  (G4 bank-spread)
            const int bo = (r * FIN + ln * 8) * 2;
            *reinterpret_cast<ushort8v*>((char*)aggT + (bo ^ ((r & 7) << 4))) = o;
        }
    }
    __syncthreads();

    // ---------------- Phase 2: GEMM ----------------
    const int wv = t >> 6;          // wave 0..3 -> cols wv*64..wv*64+63
    const int l  = t & 63;
    const int lr = l & 15;
    const int lk = (l >> 4) * 8;
    const int wc = wv * 64;
    const int srow = l >> 2;        // staging row within 16-row batch
    const int sk   = (l & 3) * 8;   // staging k offset (16B)

    f32x4 acc[4][4] = {};

    #pragma unroll 1
    for (int kt = 0; kt < K / 32; ++kt) {
        const int kg = kt * 32;
        const bool inA1 = (kg < FIN);
        if (inA1)
            gll16(&H[(size_t)(m0 + wv * 16 + srow) * FIN + kg + sk], &As[wv * 512]);
        #pragma unroll
        for (int j = 0; j < 4; ++j)
            gll16(&Bt[(size_t)(wv * 64 + j * 16 + srow) * K + kg + sk],
                  &Bs[wv * 2048 + j * 512]);
        __syncthreads();

        bf16x8 af[4], bfr[4];
        if (inA1) {
            #pragma unroll
            for (int m = 0; m < 4; ++m)
                af[m] = *reinterpret_cast<const bf16x8*>(&As[(m * 16 + lr) * 32 + lk]);
        } else {
            const int ka = kg - FIN;
            #pragma unroll
            for (int m = 0; m < 4; ++m) {
                const int r = m * 16 + lr;
                const int bo = (r * FIN + ka + lk) * 2;
                af[m] = *reinterpret_cast<const bf16x8*>((char*)aggT + (bo ^ ((r & 7) << 4)));
            }
        }
        #pragma unroll
        for (int n = 0; n < 4; ++n)
            bfr[n] = *reinterpret_cast<const bf16x8*>(&Bs[(wc + n * 16 + lr) * 32 + lk]);

        #pragma unroll
        for (int m = 0; m < 4; ++m)
            #pragma unroll
            for (int n = 0; n < 4; ++n)
                acc[m][n] = __builtin_amdgcn_mfma_f32_16x16x32_bf16(af[m], bfr[n], acc[m][n], 0, 0, 0);
        __syncthreads();
    }

    // epilogue: C/D layout col = l&15 (+n*16+wc), row = (l>>4)*4 + r' (+m*16)
    const int orow = (l >> 4) * 4;
    float bcol[4];
    #pragma unroll
    for (int n = 0; n < 4; ++n) bcol[n] = bias[wc + n * 16 + lr];

    #pragma unroll
    for (int m = 0; m < 4; ++m) {
        #pragma unroll
        for (int r = 0; r < 4; ++r) {
            const int row = m0 + m * 16 + orow + r;
            if (row < M) {
                #pragma unroll
                for (int n = 0; n < 4; ++n) {
                    const int cg = wc + n * 16 + lr;
                    float v = fmaxf(acc[m][n][r] + bcol[n], 0.f);
                    if (OUT_BF16)
                        ((u16*)Cout)[(size_t)row * N_COLS + cg] = f2bf(v);
                    else
                        ((float*)Cout)[(size_t)row * N_COLS + cg] = v;
                }
            }
        }
    }
}

// ---------------------------------------------------------------------------
// Host launch
// ---------------------------------------------------------------------------
extern "C" void kernel_launch(void* const* d_in, const int* in_sizes, int n_in,
                              void* d_out, int out_size, void* d_ws, size_t ws_size,
                              hipStream_t stream) {
    const float* x   = (const float*)d_in[0];
    const int*   src = (const int*)d_in[1];
    const int*   dst = (const int*)d_in[2];
    const float* W1  = (const float*)d_in[3];
    const float* b1  = (const float*)d_in[4];
    const float* W2  = (const float*)d_in[5];
    const float* b2  = (const float*)d_in[6];
    float* out = (float*)d_out;

    char* ws = (char*)d_ws;
    size_t off = 0;
    auto carve = [&](size_t bytes) {
        char* p = ws + off;
        off = (off + bytes + 255) & ~(size_t)255;
        return p;
    };
    int*   deg     = (int*)carve(sizeof(int) * N_NODES);
    int*   cursor  = (int*)carve(sizeof(int) * N_NODES);   // adjacent to deg -> 1 memset
    int*   row_ptr = (int*)carve(sizeof(int) * (N_NODES + 1));
    int*   part    = (int*)carve(sizeof(int) * 256);
    float* inv_deg = (float*)carve(sizeof(float) * N_NODES);
    int*   col     = (int*)carve(sizeof(int) * N_EDGES);
    u16*   xb      = (u16*)carve(sizeof(u16) * (size_t)M_PAD * F_IN);
    u16*   h1b     = (u16*)carve(sizeof(u16) * (size_t)M_PAD * F_HID);
    u16*   W1t     = (u16*)carve(sizeof(u16) * 256 * 256);
    u16*   W2t     = (u16*)carve(sizeof(u16) * 256 * 512);

    // --- CSR build ---
    hipMemsetAsync(deg, 0, ((char*)row_ptr - (char*)deg), stream);  // deg + cursor
    deg_kernel<<<dim3((N_EDGES + 255) / 256), 256, 0, stream>>>(dst, deg);
    block_sum_kernel<<<dim3(NB_SCAN), 256, 0, stream>>>(deg, part);
    part_scan_kernel<<<dim3(1), 256, 0, stream>>>(part, row_ptr);
    row_ptr_kernel<<<dim3(NB_SCAN), 256, 0, stream>>>(deg, part, row_ptr, inv_deg);
    fill_kernel<<<dim3((N_EDGES + 255) / 256), 256, 0, stream>>>(src, dst, row_ptr, cursor, col);

    // --- bf16 conversions ---
    f2bf_kernel<<<dim3((N_NODES * F_IN / 4 + 255) / 256), 256, 0, stream>>>(x, xb, N_NODES * F_IN / 4);
    wtrans<256><<<dim3(256), 256, 0, stream>>>(W1, W1t);
    wtrans<512><<<dim3(256), 256, 0, stream>>>(W2, W2t);

    // --- Layer 1 (fused agg + GEMM) ---
    fused_agg_gemm<F_IN, true><<<dim3(M_PAD / 64), 256, 0, stream>>>(
        xb, row_ptr, col, inv_deg, W1t, b1, h1b, N_NODES);

    // --- Layer 2 (fused agg + GEMM) ---
    fused_agg_gemm<F_HID, false><<<dim3(M_PAD / 64), 256, 0, stream>>>(
        h1b, row_ptr, col, inv_deg, W2t, b2, out, N_NODES);
}

// Round 7
// 256.399 us; speedup vs baseline: 1.1593x; 1.1593x over previous
//
#include <hip/hip_runtime.h>
#include <hip/hip_bf16.h>
#include <cstdint>

constexpr int N_NODES = 50000;
constexpr int N_EDGES = 800000;
constexpr int F_IN    = 128;
constexpr int F_HID   = 256;
constexpr int N_COLS  = 256;
constexpr int M_PAD   = 50048;   // 391 * 128
constexpr int NB_SCAN = (N_NODES + 255) / 256;       // 196
constexpr int NB_F2BF = (N_NODES * F_IN / 4) / 256;  // 6250 (exact)

typedef unsigned short u16;
typedef u16   ushort4v __attribute__((ext_vector_type(4)));
typedef u16   ushort8v __attribute__((ext_vector_type(8)));
typedef __bf16 bf16x8  __attribute__((ext_vector_type(8)));
typedef float  f32x4   __attribute__((ext_vector_type(4)));

__device__ __forceinline__ float bf2f(u16 u) {
    return __uint_as_float(((uint32_t)u) << 16);
}
__device__ __forceinline__ u16 f2bf(float f) {
    uint32_t u = __float_as_uint(f);
    uint32_t r = u + 0x7FFFu + ((u >> 16) & 1u);   // RNE
    return (u16)(r >> 16);
}

// async global->LDS, 16B per lane. LDS dest is wave-uniform base; HW adds lane*16.
__device__ __forceinline__ void gll16(const void* g, void* l) {
    __builtin_amdgcn_global_load_lds(
        (const __attribute__((address_space(1))) uint32_t*)(uintptr_t)g,
        (__attribute__((address_space(3))) uint32_t*)(uintptr_t)l,
        16, 0, 0);
}

// ---------------------------------------------------------------------------
// CSR build
// ---------------------------------------------------------------------------
__global__ void deg_kernel(const int* __restrict__ dst, int* __restrict__ deg) {
    int e = blockIdx.x * blockDim.x + threadIdx.x;
    if (e < N_EDGES) atomicAdd(&deg[dst[e]], 1);
}

__global__ __launch_bounds__(256) void block_sum_kernel(const int* __restrict__ deg,
                                                        int* __restrict__ part) {
    const int n = blockIdx.x * 256 + threadIdx.x;
    int v = (n < N_NODES) ? deg[n] : 0;
    #pragma unroll
    for (int o = 32; o > 0; o >>= 1) v += __shfl_down(v, o, 64);
    __shared__ int s[4];
    if ((threadIdx.x & 63) == 0) s[threadIdx.x >> 6] = v;
    __syncthreads();
    if (threadIdx.x == 0) part[blockIdx.x] = s[0] + s[1] + s[2] + s[3];
}

__global__ __launch_bounds__(256) void part_scan_kernel(int* __restrict__ part,
                                                        int* __restrict__ row_ptr) {
    __shared__ int s[256];
    const int tid = threadIdx.x;
    int v = (tid < NB_SCAN) ? part[tid] : 0;
    s[tid] = v;
    __syncthreads();
    #pragma unroll
    for (int o = 1; o < 256; o <<= 1) {
        int t = 0;
        if (tid >= o) t = s[tid - o];
        __syncthreads();
        s[tid] += t;
        __syncthreads();
    }
    if (tid < NB_SCAN) part[tid] = s[tid] - v;
    if (tid == 255) row_ptr[N_NODES] = s[255];
}

// local scan + block base -> row_ptr, inv_deg, AND cursor (fill's running ptr).
__global__ __launch_bounds__(256) void row_ptr_kernel(const int* __restrict__ deg,
                                                      const int* __restrict__ part,
                                                      int* __restrict__ row_ptr,
                                                      int* __restrict__ cursor,
                                                      float* __restrict__ inv_deg) {
    __shared__ int s[256];
    const int tid = threadIdx.x;
    const int n = blockIdx.x * 256 + tid;
    const int d = (n < N_NODES) ? deg[n] : 0;
    s[tid] = d;
    __syncthreads();
    #pragma unroll
    for (int o = 1; o < 256; o <<= 1) {
        int t = 0;
        if (tid >= o) t = s[tid - o];
        __syncthreads();
        s[tid] += t;
        __syncthreads();
    }
    if (n < N_NODES) {
        const int base = part[blockIdx.x] + s[tid] - d;
        row_ptr[n] = base;
        cursor[n]  = base;    // absolute write cursor for fill_kernel
        inv_deg[n] = (d > 0) ? (1.0f / (float)d) : 0.0f;
    }
}

// cursor[d] holds absolute position; one atomic, one store per edge.
__global__ void fill_kernel(const int* __restrict__ src, const int* __restrict__ dst,
                            int* __restrict__ cursor, int* __restrict__ col) {
    int e = blockIdx.x * blockDim.x + threadIdx.x;
    if (e < N_EDGES) {
        int pos = atomicAdd(&cursor[dst[e]], 1);
        col[pos] = src[e];
    }
}

// ---------------------------------------------------------------------------
// prep: x fp32 -> xb bf16  |  W1 -> W1t (transposed bf16)  |  W2 -> W2t
// One launch, block ranges.
// ---------------------------------------------------------------------------
__global__ __launch_bounds__(256) void prep_kernel(const float* __restrict__ x,
                                                   u16* __restrict__ xb,
                                                   const float* __restrict__ W1,
                                                   u16* __restrict__ W1t,
                                                   const float* __restrict__ W2,
                                                   u16* __restrict__ W2t) {
    const int b = blockIdx.x;
    const int tid = threadIdx.x;
    if (b < NB_F2BF) {
        const int i = b * 256 + tid;   // float4 index
        float4 v = *reinterpret_cast<const float4*>(&x[(size_t)i * 4]);
        ushort4v o;
        o.x = f2bf(v.x); o.y = f2bf(v.y); o.z = f2bf(v.z); o.w = f2bf(v.w);
        *reinterpret_cast<ushort4v*>(&xb[(size_t)i * 4]) = o;
    } else if (b < NB_F2BF + 256) {
        const int n = b - NB_F2BF;     // output col 0..255
        W1t[(size_t)n * 256 + tid] = f2bf(W1[(size_t)tid * N_COLS + n]);
    } else {
        const int n = b - (NB_F2BF + 256);
        #pragma unroll
        for (int kk = 0; kk < 2; ++kk) {
            const int k = kk * 256 + tid;
            W2t[(size_t)n * 512 + k] = f2bf(W2[(size_t)k * N_COLS + n]);
        }
    }
}

// ---------------------------------------------------------------------------
// Mean aggregation, bf16 in / bf16 out, fp32 accumulation (round-4 verbatim —
// at the per-CU vmem-path floor; do not touch).
// ---------------------------------------------------------------------------
template <int F>
__global__ __launch_bounds__(256) void agg_mean_bf16(const u16* __restrict__ feat,
                                                     const int* __restrict__ rp,
                                                     const int* __restrict__ col,
                                                     const float* __restrict__ invd,
                                                     u16* __restrict__ out) {
    constexpr int LPN = F / 8;
    constexpr int NPB = 256 / LPN;
    const int slot = threadIdx.x / LPN;
    const int ln   = threadIdx.x % LPN;
    const int n = blockIdx.x * NPB + slot;
    if (n >= N_NODES) return;
    const int beg = rp[n], end = rp[n + 1];
    float acc0[8] = {}, acc1[8] = {};
    int e = beg;
    for (; e + 3 < end; e += 4) {
        int nb0 = col[e];
        int nb1 = col[e + 1];
        int nb2 = col[e + 2];
        int nb3 = col[e + 3];
        ushort8v v0 = *reinterpret_cast<const ushort8v*>(&feat[(size_t)nb0 * F + ln * 8]);
        ushort8v v1 = *reinterpret_cast<const ushort8v*>(&feat[(size_t)nb1 * F + ln * 8]);
        ushort8v v2 = *reinterpret_cast<const ushort8v*>(&feat[(size_t)nb2 * F + ln * 8]);
        ushort8v v3 = *reinterpret_cast<const ushort8v*>(&feat[(size_t)nb3 * F + ln * 8]);
        #pragma unroll
        for (int j = 0; j < 8; ++j) acc0[j] += bf2f(v0[j]);
        #pragma unroll
        for (int j = 0; j < 8; ++j) acc1[j] += bf2f(v1[j]);
        #pragma unroll
        for (int j = 0; j < 8; ++j) acc0[j] += bf2f(v2[j]);
        #pragma unroll
        for (int j = 0; j < 8; ++j) acc1[j] += bf2f(v3[j]);
    }
    if (e + 1 < end) {
        int nb0 = col[e];
        int nb1 = col[e + 1];
        ushort8v v0 = *reinterpret_cast<const ushort8v*>(&feat[(size_t)nb0 * F + ln * 8]);
        ushort8v v1 = *reinterpret_cast<const ushort8v*>(&feat[(size_t)nb1 * F + ln * 8]);
        #pragma unroll
        for (int j = 0; j < 8; ++j) acc0[j] += bf2f(v0[j]);
        #pragma unroll
        for (int j = 0; j < 8; ++j) acc1[j] += bf2f(v1[j]);
        e += 2;
    }
    if (e < end) {
        ushort8v v = *reinterpret_cast<const ushort8v*>(&feat[(size_t)col[e] * F + ln * 8]);
        #pragma unroll
        for (int j = 0; j < 8; ++j) acc0[j] += bf2f(v[j]);
    }
    const float s = invd[n];
    ushort8v o;
    #pragma unroll
    for (int j = 0; j < 8; ++j) o[j] = f2bf((acc0[j] + acc1[j]) * s);
    *reinterpret_cast<ushort8v*>(&out[(size_t)n * F + ln * 8]) = o;
}

// ---------------------------------------------------------------------------
// C = relu([A1 | A2] @ W + b), bf16 MFMA, m97 structure (round-4 verbatim).
// 128x128 tile, BK=32, 256 threads = 4 waves, each wave 64x64 via 4x4 frags.
// ---------------------------------------------------------------------------
template <int K1, bool OUT_BF16>
__global__ __launch_bounds__(256) void gemm_bt_bf16(const u16* __restrict__ A1,
                                                    const u16* __restrict__ A2,
                                                    const u16* __restrict__ Bt,
                                                    const float* __restrict__ bias,
                                                    void* __restrict__ Cout, int M) {
    constexpr int K = 2 * K1;
    __shared__ u16 As[128 * 32];
    __shared__ u16 Bs[128 * 32];

    const int t  = threadIdx.x;
    const int wv = t >> 6;
    const int l  = t & 63;
    const int m0 = blockIdx.x * 128;
    const int n0 = blockIdx.y * 128;

    const int sr = t >> 2;
    const int sk = (t & 3) * 8;
    const int lr = l & 15;
    const int lk = (l >> 4) * 8;
    const int wr = (wv >> 1) * 64;
    const int wc = (wv & 1) * 64;

    f32x4 acc[4][4] = {};

    #pragma unroll 1
    for (int kt = 0; kt < K / 32; ++kt) {
        const int kg = kt * 32;
        const u16* Ab;
        int ka;
        if (kg < K1) { Ab = A1; ka = kg; }
        else         { Ab = A2; ka = kg - K1; }

        gll16(&Ab[(size_t)(m0 + sr) * K1 + ka + sk],       &As[wv * 512]);
        gll16(&Ab[(size_t)(m0 + sr + 64) * K1 + ka + sk],  &As[2048 + wv * 512]);
        gll16(&Bt[(size_t)(n0 + sr) * K + kg + sk],        &Bs[wv * 512]);
        gll16(&Bt[(size_t)(n0 + sr + 64) * K + kg + sk],   &Bs[2048 + wv * 512]);
        __syncthreads();

        bf16x8 af[4], bfr[4];
        #pragma unroll
        for (int m = 0; m < 4; ++m)
            af[m] = *reinterpret_cast<const bf16x8*>(&As[(wr + m * 16 + lr) * 32 + lk]);
        #pragma unroll
        for (int n = 0; n < 4; ++n)
            bfr[n] = *reinterpret_cast<const bf16x8*>(&Bs[(wc + n * 16 + lr) * 32 + lk]);

        #pragma unroll
        for (int m = 0; m < 4; ++m)
            #pragma unroll
            for (int n = 0; n < 4; ++n)
                acc[m][n] = __builtin_amdgcn_mfma_f32_16x16x32_bf16(af[m], bfr[n], acc[m][n], 0, 0, 0);
        __syncthreads();
    }

    const int orow = (l >> 4) * 4;
    float bcol[4];
    #pragma unroll
    for (int n = 0; n < 4; ++n) bcol[n] = bias[n0 + wc + n * 16 + lr];

    #pragma unroll
    for (int m = 0; m < 4; ++m) {
        #pragma unroll
        for (int r = 0; r < 4; ++r) {
            const int row = m0 + wr + m * 16 + orow + r;
            if (row < M) {
                #pragma unroll
                for (int n = 0; n < 4; ++n) {
                    const int cg = n0 + wc + n * 16 + lr;
                    float v = fmaxf(acc[m][n][r] + bcol[n], 0.f);
                    if (OUT_BF16)
                        ((u16*)Cout)[(size_t)row * N_COLS + cg] = f2bf(v);
                    else
                        ((float*)Cout)[(size_t)row * N_COLS + cg] = v;
                }
            }
        }
    }
}

// ---------------------------------------------------------------------------
// Host launch
// ---------------------------------------------------------------------------
extern "C" void kernel_launch(void* const* d_in, const int* in_sizes, int n_in,
                              void* d_out, int out_size, void* d_ws, size_t ws_size,
                              hipStream_t stream) {
    const float* x   = (const float*)d_in[0];
    const int*   src = (const int*)d_in[1];
    const int*   dst = (const int*)d_in[2];
    const float* W1  = (const float*)d_in[3];
    const float* b1  = (const float*)d_in[4];
    const float* W2  = (const float*)d_in[5];
    const float* b2  = (const float*)d_in[6];
    float* out = (float*)d_out;

    char* ws = (char*)d_ws;
    size_t off = 0;
    auto carve = [&](size_t bytes) {
        char* p = ws + off;
        off = (off + bytes + 255) & ~(size_t)255;
        return p;
    };
    int*   deg     = (int*)carve(sizeof(int) * N_NODES);
    int*   cursor  = (int*)carve(sizeof(int) * N_NODES);
    int*   row_ptr = (int*)carve(sizeof(int) * (N_NODES + 1));
    int*   part    = (int*)carve(sizeof(int) * 256);
    float* inv_deg = (float*)carve(sizeof(float) * N_NODES);
    int*   col     = (int*)carve(sizeof(int) * N_EDGES);
    u16*   xb      = (u16*)carve(sizeof(u16) * (size_t)M_PAD * F_IN);
    u16*   xnb     = (u16*)carve(sizeof(u16) * (size_t)M_PAD * F_IN);
    u16*   h1b     = (u16*)carve(sizeof(u16) * (size_t)M_PAD * F_HID);
    u16*   h1nb    = (u16*)carve(sizeof(u16) * (size_t)M_PAD * F_HID);
    u16*   W1t     = (u16*)carve(sizeof(u16) * 256 * 256);
    u16*   W2t     = (u16*)carve(sizeof(u16) * 256 * 512);

    // --- CSR build ---
    hipMemsetAsync(deg, 0, sizeof(int) * N_NODES, stream);
    deg_kernel<<<dim3((N_EDGES + 255) / 256), 256, 0, stream>>>(dst, deg);
    block_sum_kernel<<<dim3(NB_SCAN), 256, 0, stream>>>(deg, part);
    part_scan_kernel<<<dim3(1), 256, 0, stream>>>(part, row_ptr);
    row_ptr_kernel<<<dim3(NB_SCAN), 256, 0, stream>>>(deg, part, row_ptr, cursor, inv_deg);
    fill_kernel<<<dim3((N_EDGES + 255) / 256), 256, 0, stream>>>(src, dst, cursor, col);

    // --- bf16 conversions (single launch) ---
    prep_kernel<<<dim3(NB_F2BF + 512), 256, 0, stream>>>(x, xb, W1, W1t, W2, W2t);

    // --- Layer 1 ---
    agg_mean_bf16<F_IN><<<dim3((N_NODES + 15) / 16), 256, 0, stream>>>(xb, row_ptr, col, inv_deg, xnb);
    gemm_bt_bf16<128, true><<<dim3(M_PAD / 128, 2), 256, 0, stream>>>(xb, xnb, W1t, b1, h1b, N_NODES);

    // --- Layer 2 ---
    agg_mean_bf16<F_HID><<<dim3((N_NODES + 7) / 8), 256, 0, stream>>>(h1b, row_ptr, col, inv_deg, h1nb);
    gemm_bt_bf16<256, false><<<dim3(M_PAD / 128, 2), 256, 0, stream>>>(h1b, h1nb, W2t, b2, out, N_NODES);
}

// Round 8
// 232.712 us; speedup vs baseline: 1.2773x; 1.1018x over previous
//
#include <hip/hip_runtime.h>
#include <hip/hip_bf16.h>
#include <cstdint>

constexpr int N_NODES = 50000;
constexpr int N_EDGES = 800000;
constexpr int F_IN    = 128;
constexpr int F_HID   = 256;
constexpr int N_COLS  = 256;
constexpr int M_PAD   = 50176;   // 392 * 128
constexpr int NB_SCAN = (N_NODES + 255) / 256;       // 196
constexpr int NB_DEG  = N_EDGES / 256;               // 3125 (exact)
constexpr int NB_F2BF = (N_NODES * F_IN / 4) / 256;  // 6250 (exact)

typedef unsigned short u16;
typedef u16   ushort4v __attribute__((ext_vector_type(4)));
typedef u16   ushort8v __attribute__((ext_vector_type(8)));
typedef __bf16 bf16x8  __attribute__((ext_vector_type(8)));
typedef float  f32x4   __attribute__((ext_vector_type(4)));

__device__ __forceinline__ float bf2f(u16 u) {
    return __uint_as_float(((uint32_t)u) << 16);
}
__device__ __forceinline__ u16 f2bf(float f) {
    uint32_t u = __float_as_uint(f);
    uint32_t r = u + 0x7FFFu + ((u >> 16) & 1u);   // RNE
    return (u16)(r >> 16);
}

// async global->LDS, 16B per lane. LDS dest is wave-uniform base; HW adds lane*16.
__device__ __forceinline__ void gll16(const void* g, void* l) {
    __builtin_amdgcn_global_load_lds(
        (const __attribute__((address_space(1))) uint32_t*)(uintptr_t)g,
        (__attribute__((address_space(3))) uint32_t*)(uintptr_t)l,
        16, 0, 0);
}

// ---------------------------------------------------------------------------
// deg histogram + fp32->bf16 conversions, fused into one launch (block ranges)
// ---------------------------------------------------------------------------
__global__ __launch_bounds__(256) void deg_prep_kernel(const int* __restrict__ dst,
                                                       int* __restrict__ deg,
                                                       const float* __restrict__ x,
                                                       u16* __restrict__ xb,
                                                       const float* __restrict__ W1,
                                                       u16* __restrict__ W1t,
                                                       const float* __restrict__ W2,
                                                       u16* __restrict__ W2t) {
    const int b = blockIdx.x;
    const int tid = threadIdx.x;
    if (b < NB_DEG) {
        atomicAdd(&deg[dst[b * 256 + tid]], 1);
    } else if (b < NB_DEG + NB_F2BF) {
        const int i = (b - NB_DEG) * 256 + tid;   // float4 index
        float4 v = *reinterpret_cast<const float4*>(&x[(size_t)i * 4]);
        ushort4v o;
        o.x = f2bf(v.x); o.y = f2bf(v.y); o.z = f2bf(v.z); o.w = f2bf(v.w);
        *reinterpret_cast<ushort4v*>(&xb[(size_t)i * 4]) = o;
    } else if (b < NB_DEG + NB_F2BF + 256) {
        const int n = b - (NB_DEG + NB_F2BF);     // W1 output col 0..255
        W1t[(size_t)n * 256 + tid] = f2bf(W1[(size_t)tid * N_COLS + n]);
    } else {
        const int n = b - (NB_DEG + NB_F2BF + 256);
        #pragma unroll
        for (int kk = 0; kk < 2; ++kk) {
            const int k = kk * 256 + tid;
            W2t[(size_t)n * 512 + k] = f2bf(W2[(size_t)k * N_COLS + n]);
        }
    }
}

// ---------------------------------------------------------------------------
// CSR build (two-level scan)
// ---------------------------------------------------------------------------
__global__ __launch_bounds__(256) void block_sum_kernel(const int* __restrict__ deg,
                                                        int* __restrict__ part) {
    const int n = blockIdx.x * 256 + threadIdx.x;
    int v = (n < N_NODES) ? deg[n] : 0;
    #pragma unroll
    for (int o = 32; o > 0; o >>= 1) v += __shfl_down(v, o, 64);
    __shared__ int s[4];
    if ((threadIdx.x & 63) == 0) s[threadIdx.x >> 6] = v;
    __syncthreads();
    if (threadIdx.x == 0) part[blockIdx.x] = s[0] + s[1] + s[2] + s[3];
}

__global__ __launch_bounds__(256) void part_scan_kernel(int* __restrict__ part,
                                                        int* __restrict__ row_ptr) {
    __shared__ int s[256];
    const int tid = threadIdx.x;
    int v = (tid < NB_SCAN) ? part[tid] : 0;
    s[tid] = v;
    __syncthreads();
    #pragma unroll
    for (int o = 1; o < 256; o <<= 1) {
        int t = 0;
        if (tid >= o) t = s[tid - o];
        __syncthreads();
        s[tid] += t;
        __syncthreads();
    }
    if (tid < NB_SCAN) part[tid] = s[tid] - v;
    if (tid == 255) row_ptr[N_NODES] = s[255];
}

__global__ __launch_bounds__(256) void row_ptr_kernel(const int* __restrict__ deg,
                                                      const int* __restrict__ part,
                                                      int* __restrict__ row_ptr,
                                                      int* __restrict__ cursor,
                                                      float* __restrict__ inv_deg) {
    __shared__ int s[256];
    const int tid = threadIdx.x;
    const int n = blockIdx.x * 256 + tid;
    const int d = (n < N_NODES) ? deg[n] : 0;
    s[tid] = d;
    __syncthreads();
    #pragma unroll
    for (int o = 1; o < 256; o <<= 1) {
        int t = 0;
        if (tid >= o) t = s[tid - o];
        __syncthreads();
        s[tid] += t;
        __syncthreads();
    }
    if (n < N_NODES) {
        const int base = part[blockIdx.x] + s[tid] - d;
        row_ptr[n] = base;
        cursor[n]  = base;
        inv_deg[n] = (d > 0) ? (1.0f / (float)d) : 0.0f;
    }
}

__global__ void fill_kernel(const int* __restrict__ src, const int* __restrict__ dst,
                            int* __restrict__ cursor, int* __restrict__ col) {
    int e = blockIdx.x * blockDim.x + threadIdx.x;
    if (e < N_EDGES) {
        int pos = atomicAdd(&cursor[dst[e]], 1);
        col[pos] = src[e];
    }
}

// ---------------------------------------------------------------------------
// Column-sliced, XCD-pinned mean aggregation.
// Feature dim split into SLICES slices of 64 cols; each slice pinned to
// 8/SLICES XCDs via blockIdx%8 -> per-XCD gather working set = 50k*128B =
// 6.4MB (~L2-sized) instead of the whole table. Same per-lane math/rounding
// as before (8-float acc pair, 4 edges in flight).
// ---------------------------------------------------------------------------
template <int F, int SLICES>
__global__ __launch_bounds__(256) void agg_mean_sliced(const u16* __restrict__ feat,
                                                       const int* __restrict__ rp,
                                                       const int* __restrict__ col,
                                                       const float* __restrict__ invd,
                                                       u16* __restrict__ out) {
    static_assert(F / SLICES == 64, "slice width must be 64 cols");
    constexpr int XPS    = 8 / SLICES;                  // XCDs per slice
    constexpr int NCHUNK = (N_NODES + 31) / 32;         // 1563 node-chunks
    constexpr int CPX    = (NCHUNK + XPS - 1) / XPS;    // chunks per XCD
    const int bid  = blockIdx.x;
    const int x    = bid & 7;           // intended XCD (round-robin heuristic)
    const int s    = x / XPS;           // column slice
    const int part = x % XPS;           // node partition within slice
    const int chunk = part * CPX + (bid >> 3);
    const int slot = threadIdx.x >> 3;  // 0..31 node within chunk
    const int ln   = threadIdx.x & 7;   // 0..7 lane within 64-col slice
    const int n = chunk * 32 + slot;
    if (n >= N_NODES) return;

    const u16* ft = feat + s * 64 + ln * 8;   // gather base for this slice
    const int beg = rp[n], end = rp[n + 1];
    float acc0[8] = {}, acc1[8] = {};
    int e = beg;
    for (; e + 3 < end; e += 4) {
        int nb0 = col[e];
        int nb1 = col[e + 1];
        int nb2 = col[e + 2];
        int nb3 = col[e + 3];
        ushort8v v0 = *reinterpret_cast<const ushort8v*>(&ft[(size_t)nb0 * F]);
        ushort8v v1 = *reinterpret_cast<const ushort8v*>(&ft[(size_t)nb1 * F]);
        ushort8v v2 = *reinterpret_cast<const ushort8v*>(&ft[(size_t)nb2 * F]);
        ushort8v v3 = *reinterpret_cast<const ushort8v*>(&ft[(size_t)nb3 * F]);
        #pragma unroll
        for (int j = 0; j < 8; ++j) acc0[j] += bf2f(v0[j]);
        #pragma unroll
        for (int j = 0; j < 8; ++j) acc1[j] += bf2f(v1[j]);
        #pragma unroll
        for (int j = 0; j < 8; ++j) acc0[j] += bf2f(v2[j]);
        #pragma unroll
        for (int j = 0; j < 8; ++j) acc1[j] += bf2f(v3[j]);
    }
    if (e + 1 < end) {
        int nb0 = col[e];
        int nb1 = col[e + 1];
        ushort8v v0 = *reinterpret_cast<const ushort8v*>(&ft[(size_t)nb0 * F]);
        ushort8v v1 = *reinterpret_cast<const ushort8v*>(&ft[(size_t)nb1 * F]);
        #pragma unroll
        for (int j = 0; j < 8; ++j) acc0[j] += bf2f(v0[j]);
        #pragma unroll
        for (int j = 0; j < 8; ++j) acc1[j] += bf2f(v1[j]);
        e += 2;
    }
    if (e < end) {
        ushort8v v = *reinterpret_cast<const ushort8v*>(&ft[(size_t)col[e] * F]);
        #pragma unroll
        for (int j = 0; j < 8; ++j) acc0[j] += bf2f(v[j]);
    }
    const float sc = invd[n];
    ushort8v o;
    #pragma unroll
    for (int j = 0; j < 8; ++j) o[j] = f2bf((acc0[j] + acc1[j]) * sc);
    *reinterpret_cast<ushort8v*>(&out[(size_t)n * F + s * 64 + ln * 8]) = o;
}

// ---------------------------------------------------------------------------
// C = relu([A1 | A2] @ W + b), bf16 MFMA, m97 structure.
// 1D grid of 784 blocks, XCD-paired: the two n-tiles sharing an A-panel sit
// 8 apart in blockIdx (same XCD) so the second A read is an L2 hit.
// ---------------------------------------------------------------------------
template <int K1, bool OUT_BF16>
__global__ __launch_bounds__(256) void gemm_bt_bf16(const u16* __restrict__ A1,
                                                    const u16* __restrict__ A2,
                                                    const u16* __restrict__ Bt,
                                                    const float* __restrict__ bias,
                                                    void* __restrict__ Cout, int M) {
    constexpr int K = 2 * K1;
    __shared__ u16 As[128 * 32];
    __shared__ u16 Bs[128 * 32];

    const int t  = threadIdx.x;
    const int wv = t >> 6;
    const int l  = t & 63;
    // bid -> (mt, nt): g=bid>>4, r=bid&15, mt=g*8+(r&7), nt=r>>3
    const int g  = blockIdx.x >> 4;
    const int r  = blockIdx.x & 15;
    const int m0 = (g * 8 + (r & 7)) * 128;
    const int n0 = (r >> 3) * 128;

    const int sr = t >> 2;
    const int sk = (t & 3) * 8;
    const int lr = l & 15;
    const int lk = (l >> 4) * 8;
    const int wr = (wv >> 1) * 64;
    const int wc = (wv & 1) * 64;

    f32x4 acc[4][4] = {};

    #pragma unroll 1
    for (int kt = 0; kt < K / 32; ++kt) {
        const int kg = kt * 32;
        const u16* Ab;
        int ka;
        if (kg < K1) { Ab = A1; ka = kg; }
        else         { Ab = A2; ka = kg - K1; }

        gll16(&Ab[(size_t)(m0 + sr) * K1 + ka + sk],       &As[wv * 512]);
        gll16(&Ab[(size_t)(m0 + sr + 64) * K1 + ka + sk],  &As[2048 + wv * 512]);
        gll16(&Bt[(size_t)(n0 + sr) * K + kg + sk],        &Bs[wv * 512]);
        gll16(&Bt[(size_t)(n0 + sr + 64) * K + kg + sk],   &Bs[2048 + wv * 512]);
        __syncthreads();

        bf16x8 af[4], bfr[4];
        #pragma unroll
        for (int m = 0; m < 4; ++m)
            af[m] = *reinterpret_cast<const bf16x8*>(&As[(wr + m * 16 + lr) * 32 + lk]);
        #pragma unroll
        for (int n = 0; n < 4; ++n)
            bfr[n] = *reinterpret_cast<const bf16x8*>(&Bs[(wc + n * 16 + lr) * 32 + lk]);

        #pragma unroll
        for (int m = 0; m < 4; ++m)
            #pragma unroll
            for (int n = 0; n < 4; ++n)
                acc[m][n] = __builtin_amdgcn_mfma_f32_16x16x32_bf16(af[m], bfr[n], acc[m][n], 0, 0, 0);
        __syncthreads();
    }

    const int orow = (l >> 4) * 4;
    float bcol[4];
    #pragma unroll
    for (int n = 0; n < 4; ++n) bcol[n] = bias[n0 + wc + n * 16 + lr];

    #pragma unroll
    for (int m = 0; m < 4; ++m) {
        #pragma unroll
        for (int r2 = 0; r2 < 4; ++r2) {
            const int row = m0 + wr + m * 16 + orow + r2;
            if (row < M) {
                #pragma unroll
                for (int n = 0; n < 4; ++n) {
                    const int cg = n0 + wc + n * 16 + lr;
                    float v = fmaxf(acc[m][n][r2] + bcol[n], 0.f);
                    if (OUT_BF16)
                        ((u16*)Cout)[(size_t)row * N_COLS + cg] = f2bf(v);
                    else
                        ((float*)Cout)[(size_t)row * N_COLS + cg] = v;
                }
            }
        }
    }
}

// ---------------------------------------------------------------------------
// Host launch
// ---------------------------------------------------------------------------
extern "C" void kernel_launch(void* const* d_in, const int* in_sizes, int n_in,
                              void* d_out, int out_size, void* d_ws, size_t ws_size,
                              hipStream_t stream) {
    const float* x   = (const float*)d_in[0];
    const int*   src = (const int*)d_in[1];
    const int*   dst = (const int*)d_in[2];
    const float* W1  = (const float*)d_in[3];
    const float* b1  = (const float*)d_in[4];
    const float* W2  = (const float*)d_in[5];
    const float* b2  = (const float*)d_in[6];
    float* out = (float*)d_out;

    char* ws = (char*)d_ws;
    size_t off = 0;
    auto carve = [&](size_t bytes) {
        char* p = ws + off;
        off = (off + bytes + 255) & ~(size_t)255;
        return p;
    };
    int*   deg     = (int*)carve(sizeof(int) * N_NODES);
    int*   cursor  = (int*)carve(sizeof(int) * N_NODES);
    int*   row_ptr = (int*)carve(sizeof(int) * (N_NODES + 1));
    int*   part    = (int*)carve(sizeof(int) * 256);
    float* inv_deg = (float*)carve(sizeof(float) * N_NODES);
    int*   col     = (int*)carve(sizeof(int) * N_EDGES);
    u16*   xb      = (u16*)carve(sizeof(u16) * (size_t)M_PAD * F_IN);
    u16*   xnb     = (u16*)carve(sizeof(u16) * (size_t)M_PAD * F_IN);
    u16*   h1b     = (u16*)carve(sizeof(u16) * (size_t)M_PAD * F_HID);
    u16*   h1nb    = (u16*)carve(sizeof(u16) * (size_t)M_PAD * F_HID);
    u16*   W1t     = (u16*)carve(sizeof(u16) * 256 * 256);
    u16*   W2t     = (u16*)carve(sizeof(u16) * 256 * 512);

    // --- CSR build + conversions ---
    hipMemsetAsync(deg, 0, sizeof(int) * N_NODES, stream);
    deg_prep_kernel<<<dim3(NB_DEG + NB_F2BF + 512), 256, 0, stream>>>(
        dst, deg, x, xb, W1, W1t, W2, W2t);
    block_sum_kernel<<<dim3(NB_SCAN), 256, 0, stream>>>(deg, part);
    part_scan_kernel<<<dim3(1), 256, 0, stream>>>(part, row_ptr);
    row_ptr_kernel<<<dim3(NB_SCAN), 256, 0, stream>>>(deg, part, row_ptr, cursor, inv_deg);
    fill_kernel<<<dim3((N_EDGES + 255) / 256), 256, 0, stream>>>(src, dst, cursor, col);

    // --- Layer 1 ---
    {
        constexpr int CPX = ((N_NODES + 31) / 32 + 3) / 4;   // 391
        agg_mean_sliced<F_IN, 2><<<dim3(8 * CPX), 256, 0, stream>>>(
            xb, row_ptr, col, inv_deg, xnb);
    }
    gemm_bt_bf16<128, true><<<dim3(784), 256, 0, stream>>>(xb, xnb, W1t, b1, h1b, N_NODES);

    // --- Layer 2 ---
    {
        constexpr int CPX = ((N_NODES + 31) / 32 + 1) / 2;   // 782
        agg_mean_sliced<F_HID, 4><<<dim3(8 * CPX), 256, 0, stream>>>(
            h1b, row_ptr, col, inv_deg, h1nb);
    }
    gemm_bt_bf16<256, false><<<dim3(784), 256, 0, stream>>>(h1b, h1nb, W2t, b2, out, N_NODES);
}

// Round 9
// 173.082 us; speedup vs baseline: 1.7174x; 1.3445x over previous
//
#include <hip/hip_runtime.h>
#include <hip/hip_bf16.h>
#include <cstdint>

constexpr int N_NODES = 50000;
constexpr int N_EDGES = 800000;
constexpr int F_IN    = 128;
constexpr int F_HID   = 256;
constexpr int N_COLS  = 256;
constexpr int M_PAD   = 50176;   // 392 * 128
constexpr int NB_F2BF = (N_NODES * F_IN / 4) / 256;  // 6250 (exact)

// CSR build via bucketed counting sort
constexpr int EPB     = 4096;                         // edges per partition block
constexpr int NB_PART = (N_EDGES + EPB - 1) / EPB;    // 196
constexpr int NBUCK   = (N_NODES + 255) / 256;        // 196 buckets (dst>>8)

typedef unsigned short u16;
typedef u16   ushort4v __attribute__((ext_vector_type(4)));
typedef u16   ushort8v __attribute__((ext_vector_type(8)));
typedef __bf16 bf16x8  __attribute__((ext_vector_type(8)));
typedef float  f32x4   __attribute__((ext_vector_type(4)));

__device__ __forceinline__ float bf2f(u16 u) {
    return __uint_as_float(((uint32_t)u) << 16);
}
__device__ __forceinline__ u16 f2bf(float f) {
    uint32_t u = __float_as_uint(f);
    uint32_t r = u + 0x7FFFu + ((u >> 16) & 1u);   // RNE
    return (u16)(r >> 16);
}

// async global->LDS, 16B per lane. LDS dest is wave-uniform base; HW adds lane*16.
__device__ __forceinline__ void gll16(const void* g, void* l) {
    __builtin_amdgcn_global_load_lds(
        (const __attribute__((address_space(1))) uint32_t*)(uintptr_t)g,
        (__attribute__((address_space(3))) uint32_t*)(uintptr_t)l,
        16, 0, 0);
}

// ---------------------------------------------------------------------------
// P1: per-block bucket histogram (LDS only, no global atomics).
// hist[block][bin], bin = dst >> 8.
// ---------------------------------------------------------------------------
__global__ __launch_bounds__(256) void hist_kernel(const int* __restrict__ dst,
                                                   int* __restrict__ hist) {
    __shared__ int h[256];
    const int t = threadIdx.x;
    h[t] = 0;
    __syncthreads();
    const int base = blockIdx.x * EPB;
    #pragma unroll
    for (int i = 0; i < EPB / 256; ++i) {
        const int e = base + i * 256 + t;
        if (e < N_EDGES) atomicAdd(&h[dst[e] >> 8], 1);
    }
    __syncthreads();
    hist[blockIdx.x * 256 + t] = h[t];
}

// ---------------------------------------------------------------------------
// S1: per-bin scan across blocks. block b: hist[t][b] -> exclusive prefix;
// bin_tot[b] = total.
// ---------------------------------------------------------------------------
__global__ __launch_bounds__(256) void colscan_kernel(int* __restrict__ hist,
                                                      int* __restrict__ bin_tot) {
    __shared__ int s[256];
    const int b = blockIdx.x;
    const int t = threadIdx.x;
    const int v = (t < NB_PART) ? hist[t * 256 + b] : 0;
    s[t] = v;
    __syncthreads();
    #pragma unroll
    for (int o = 1; o < 256; o <<= 1) {
        int tv = 0;
        if (t >= o) tv = s[t - o];
        __syncthreads();
        s[t] += tv;
        __syncthreads();
    }
    if (t < NB_PART) hist[t * 256 + b] = s[t] - v;
    if (t == 255) bin_tot[b] = s[255];
}

// ---------------------------------------------------------------------------
// S2: exclusive scan of bin totals -> bin_base. Also row_ptr[N] = E.
// ---------------------------------------------------------------------------
__global__ __launch_bounds__(256) void binscan_kernel(const int* __restrict__ bin_tot,
                                                      int* __restrict__ bin_base,
                                                      int* __restrict__ row_ptr) {
    __shared__ int s[256];
    const int t = threadIdx.x;
    const int v = (t < NBUCK) ? bin_tot[t] : 0;
    s[t] = v;
    __syncthreads();
    #pragma unroll
    for (int o = 1; o < 256; o <<= 1) {
        int tv = 0;
        if (t >= o) tv = s[t - o];
        __syncthreads();
        s[t] += tv;
        __syncthreads();
    }
    bin_base[t] = s[t] - v;   // t >= NBUCK gives N_EDGES (used as eend of last bucket)
    if (t == 0) row_ptr[N_NODES] = N_EDGES;
}

// ---------------------------------------------------------------------------
// P2: partition edges into bucket-contiguous ebuf (src,dst pairs).
// Per-(block,bin) chunks are contiguous -> near-full-line writebacks.
// ---------------------------------------------------------------------------
__global__ __launch_bounds__(256) void scatter_kernel(const int* __restrict__ src,
                                                      const int* __restrict__ dst,
                                                      const int* __restrict__ hist,
                                                      const int* __restrict__ bin_base,
                                                      int2* __restrict__ ebuf) {
    __shared__ int cur[256];
    const int t = threadIdx.x;
    cur[t] = bin_base[t] + hist[blockIdx.x * 256 + t];
    __syncthreads();
    const int base = blockIdx.x * EPB;
    #pragma unroll
    for (int i = 0; i < EPB / 256; ++i) {
        const int e = base + i * 256 + t;
        if (e < N_EDGES) {
            const int d = dst[e];
            const int pos = atomicAdd(&cur[d >> 8], 1);
            ebuf[pos] = make_int2(src[e], d);
        }
    }
}

// ---------------------------------------------------------------------------
// P3: one block per bucket (256 nodes): LDS deg-count -> LDS scan ->
// row_ptr/inv_deg (coalesced) -> col scatter into the bucket's own 16KB
// region (XCD-local, LDS cursors only).
// ---------------------------------------------------------------------------
__global__ __launch_bounds__(256) void bucket_fill_kernel(const int2* __restrict__ ebuf,
                                                          const int* __restrict__ bin_base,
                                                          int* __restrict__ row_ptr,
                                                          float* __restrict__ inv_deg,
                                                          int* __restrict__ col) {
    __shared__ int cnt[256];
    __shared__ int scn[256];
    __shared__ int cur[256];
    const int blk = blockIdx.x;
    const int t = threadIdx.x;
    const int ebeg = bin_base[blk];
    const int eend = bin_base[blk + 1];
    const int nb0 = blk << 8;

    cnt[t] = 0;
    __syncthreads();
    for (int e = ebeg + t; e < eend; e += 256)
        atomicAdd(&cnt[ebuf[e].y & 255], 1);
    __syncthreads();
    const int d = cnt[t];
    scn[t] = d;
    __syncthreads();
    #pragma unroll
    for (int o = 1; o < 256; o <<= 1) {
        int tv = 0;
        if (t >= o) tv = scn[t - o];
        __syncthreads();
        scn[t] += tv;
        __syncthreads();
    }
    const int off = scn[t] - d;
    const int n = nb0 + t;
    if (n < N_NODES) {
        row_ptr[n] = ebeg + off;
        inv_deg[n] = (d > 0) ? (1.0f / (float)d) : 0.0f;
    }
    cur[t] = off;
    __syncthreads();
    for (int e = ebeg + t; e < eend; e += 256) {
        const int2 p = ebuf[e];
        col[ebeg + atomicAdd(&cur[p.y & 255], 1)] = p.x;
    }
}

// ---------------------------------------------------------------------------
// prep: x fp32 -> xb bf16  |  W1 -> W1t (transposed bf16)  |  W2 -> W2t
// ---------------------------------------------------------------------------
__global__ __launch_bounds__(256) void prep_kernel(const float* __restrict__ x,
                                                   u16* __restrict__ xb,
                                                   const float* __restrict__ W1,
                                                   u16* __restrict__ W1t,
                                                   const float* __restrict__ W2,
                                                   u16* __restrict__ W2t) {
    const int b = blockIdx.x;
    const int tid = threadIdx.x;
    if (b < NB_F2BF) {
        const int i = b * 256 + tid;   // float4 index
        float4 v = *reinterpret_cast<const float4*>(&x[(size_t)i * 4]);
        ushort4v o;
        o.x = f2bf(v.x); o.y = f2bf(v.y); o.z = f2bf(v.z); o.w = f2bf(v.w);
        *reinterpret_cast<ushort4v*>(&xb[(size_t)i * 4]) = o;
    } else if (b < NB_F2BF + 256) {
        const int n = b - NB_F2BF;
        W1t[(size_t)n * 256 + tid] = f2bf(W1[(size_t)tid * N_COLS + n]);
    } else {
        const int n = b - (NB_F2BF + 256);
        #pragma unroll
        for (int kk = 0; kk < 2; ++kk) {
            const int k = kk * 256 + tid;
            W2t[(size_t)n * 512 + k] = f2bf(W2[(size_t)k * N_COLS + n]);
        }
    }
}

// ---------------------------------------------------------------------------
// Column-sliced, XCD-pinned mean aggregation (round-8 verbatim).
// ---------------------------------------------------------------------------
template <int F, int SLICES>
__global__ __launch_bounds__(256) void agg_mean_sliced(const u16* __restrict__ feat,
                                                       const int* __restrict__ rp,
                                                       const int* __restrict__ col,
                                                       const float* __restrict__ invd,
                                                       u16* __restrict__ out) {
    static_assert(F / SLICES == 64, "slice width must be 64 cols");
    constexpr int XPS    = 8 / SLICES;
    constexpr int NCHUNK = (N_NODES + 31) / 32;
    constexpr int CPX    = (NCHUNK + XPS - 1) / XPS;
    const int bid  = blockIdx.x;
    const int x    = bid & 7;
    const int s    = x / XPS;
    const int part = x % XPS;
    const int chunk = part * CPX + (bid >> 3);
    const int slot = threadIdx.x >> 3;
    const int ln   = threadIdx.x & 7;
    const int n = chunk * 32 + slot;
    if (n >= N_NODES) return;

    const u16* ft = feat + s * 64 + ln * 8;
    const int beg = rp[n], end = rp[n + 1];
    float acc0[8] = {}, acc1[8] = {};
    int e = beg;
    for (; e + 3 < end; e += 4) {
        int nb0 = col[e];
        int nb1 = col[e + 1];
        int nb2 = col[e + 2];
        int nb3 = col[e + 3];
        ushort8v v0 = *reinterpret_cast<const ushort8v*>(&ft[(size_t)nb0 * F]);
        ushort8v v1 = *reinterpret_cast<const ushort8v*>(&ft[(size_t)nb1 * F]);
        ushort8v v2 = *reinterpret_cast<const ushort8v*>(&ft[(size_t)nb2 * F]);
        ushort8v v3 = *reinterpret_cast<const ushort8v*>(&ft[(size_t)nb3 * F]);
        #pragma unroll
        for (int j = 0; j < 8; ++j) acc0[j] += bf2f(v0[j]);
        #pragma unroll
        for (int j = 0; j < 8; ++j) acc1[j] += bf2f(v1[j]);
        #pragma unroll
        for (int j = 0; j < 8; ++j) acc0[j] += bf2f(v2[j]);
        #pragma unroll
        for (int j = 0; j < 8; ++j) acc1[j] += bf2f(v3[j]);
    }
    if (e + 1 < end) {
        int nb0 = col[e];
        int nb1 = col[e + 1];
        ushort8v v0 = *reinterpret_cast<const ushort8v*>(&ft[(size_t)nb0 * F]);
        ushort8v v1 = *reinterpret_cast<const ushort8v*>(&ft[(size_t)nb1 * F]);
        #pragma unroll
        for (int j = 0; j < 8; ++j) acc0[j] += bf2f(v0[j]);
        #pragma unroll
        for (int j = 0; j < 8; ++j) acc1[j] += bf2f(v1[j]);
        e += 2;
    }
    if (e < end) {
        ushort8v v = *reinterpret_cast<const ushort8v*>(&ft[(size_t)col[e] * F]);
        #pragma unroll
        for (int j = 0; j < 8; ++j) acc0[j] += bf2f(v[j]);
    }
    const float sc = invd[n];
    ushort8v o;
    #pragma unroll
    for (int j = 0; j < 8; ++j) o[j] = f2bf((acc0[j] + acc1[j]) * sc);
    *reinterpret_cast<ushort8v*>(&out[(size_t)n * F + s * 64 + ln * 8]) = o;
}

// ---------------------------------------------------------------------------
// C = relu([A1 | A2] @ W + b), bf16 MFMA, m97 structure, XCD-paired n-tiles
// (round-8 verbatim).
// ---------------------------------------------------------------------------
template <int K1, bool OUT_BF16>
__global__ __launch_bounds__(256) void gemm_bt_bf16(const u16* __restrict__ A1,
                                                    const u16* __restrict__ A2,
                                                    const u16* __restrict__ Bt,
                                                    const float* __restrict__ bias,
                                                    void* __restrict__ Cout, int M) {
    constexpr int K = 2 * K1;
    __shared__ u16 As[128 * 32];
    __shared__ u16 Bs[128 * 32];

    const int t  = threadIdx.x;
    const int wv = t >> 6;
    const int l  = t & 63;
    const int g  = blockIdx.x >> 4;
    const int r  = blockIdx.x & 15;
    const int m0 = (g * 8 + (r & 7)) * 128;
    const int n0 = (r >> 3) * 128;

    const int sr = t >> 2;
    const int sk = (t & 3) * 8;
    const int lr = l & 15;
    const int lk = (l >> 4) * 8;
    const int wr = (wv >> 1) * 64;
    const int wc = (wv & 1) * 64;

    f32x4 acc[4][4] = {};

    #pragma unroll 1
    for (int kt = 0; kt < K / 32; ++kt) {
        const int kg = kt * 32;
        const u16* Ab;
        int ka;
        if (kg < K1) { Ab = A1; ka = kg; }
        else         { Ab = A2; ka = kg - K1; }

        gll16(&Ab[(size_t)(m0 + sr) * K1 + ka + sk],       &As[wv * 512]);
        gll16(&Ab[(size_t)(m0 + sr + 64) * K1 + ka + sk],  &As[2048 + wv * 512]);
        gll16(&Bt[(size_t)(n0 + sr) * K + kg + sk],        &Bs[wv * 512]);
        gll16(&Bt[(size_t)(n0 + sr + 64) * K + kg + sk],   &Bs[2048 + wv * 512]);
        __syncthreads();

        bf16x8 af[4], bfr[4];
        #pragma unroll
        for (int m = 0; m < 4; ++m)
            af[m] = *reinterpret_cast<const bf16x8*>(&As[(wr + m * 16 + lr) * 32 + lk]);
        #pragma unroll
        for (int n = 0; n < 4; ++n)
            bfr[n] = *reinterpret_cast<const bf16x8*>(&Bs[(wc + n * 16 + lr) * 32 + lk]);

        #pragma unroll
        for (int m = 0; m < 4; ++m)
            #pragma unroll
            for (int n = 0; n < 4; ++n)
                acc[m][n] = __builtin_amdgcn_mfma_f32_16x16x32_bf16(af[m], bfr[n], acc[m][n], 0, 0, 0);
        __syncthreads();
    }

    const int orow = (l >> 4) * 4;
    float bcol[4];
    #pragma unroll
    for (int n = 0; n < 4; ++n) bcol[n] = bias[n0 + wc + n * 16 + lr];

    #pragma unroll
    for (int m = 0; m < 4; ++m) {
        #pragma unroll
        for (int r2 = 0; r2 < 4; ++r2) {
            const int row = m0 + wr + m * 16 + orow + r2;
            if (row < M) {
                #pragma unroll
                for (int n = 0; n < 4; ++n) {
                    const int cg = n0 + wc + n * 16 + lr;
                    float v = fmaxf(acc[m][n][r2] + bcol[n], 0.f);
                    if (OUT_BF16)
                        ((u16*)Cout)[(size_t)row * N_COLS + cg] = f2bf(v);
                    else
                        ((float*)Cout)[(size_t)row * N_COLS + cg] = v;
                }
            }
        }
    }
}

// ---------------------------------------------------------------------------
// Host launch
// ---------------------------------------------------------------------------
extern "C" void kernel_launch(void* const* d_in, const int* in_sizes, int n_in,
                              void* d_out, int out_size, void* d_ws, size_t ws_size,
                              hipStream_t stream) {
    const float* x   = (const float*)d_in[0];
    const int*   src = (const int*)d_in[1];
    const int*   dst = (const int*)d_in[2];
    const float* W1  = (const float*)d_in[3];
    const float* b1  = (const float*)d_in[4];
    const float* W2  = (const float*)d_in[5];
    const float* b2  = (const float*)d_in[6];
    float* out = (float*)d_out;

    char* ws = (char*)d_ws;
    size_t off = 0;
    auto carve = [&](size_t bytes) {
        char* p = ws + off;
        off = (off + bytes + 255) & ~(size_t)255;
        return p;
    };
    int*   row_ptr  = (int*)carve(sizeof(int) * (N_NODES + 1));
    float* inv_deg  = (float*)carve(sizeof(float) * N_NODES);
    int*   col      = (int*)carve(sizeof(int) * N_EDGES);
    int*   hist     = (int*)carve(sizeof(int) * NB_PART * 256);
    int*   bin_tot  = (int*)carve(sizeof(int) * 256);
    int*   bin_base = (int*)carve(sizeof(int) * 256);
    int2*  ebuf     = (int2*)carve(sizeof(int2) * N_EDGES);
    u16*   xb       = (u16*)carve(sizeof(u16) * (size_t)M_PAD * F_IN);
    u16*   xnb      = (u16*)carve(sizeof(u16) * (size_t)M_PAD * F_IN);
    u16*   h1b      = (u16*)carve(sizeof(u16) * (size_t)M_PAD * F_HID);
    u16*   h1nb     = (u16*)carve(sizeof(u16) * (size_t)M_PAD * F_HID);
    u16*   W1t      = (u16*)carve(sizeof(u16) * 256 * 256);
    u16*   W2t      = (u16*)carve(sizeof(u16) * 256 * 512);

    // --- CSR build: bucketed counting sort (no global atomics, no memset) ---
    hist_kernel<<<dim3(NB_PART), 256, 0, stream>>>(dst, hist);
    colscan_kernel<<<dim3(NBUCK), 256, 0, stream>>>(hist, bin_tot);
    binscan_kernel<<<dim3(1), 256, 0, stream>>>(bin_tot, bin_base, row_ptr);
    scatter_kernel<<<dim3(NB_PART), 256, 0, stream>>>(src, dst, hist, bin_base, ebuf);
    bucket_fill_kernel<<<dim3(NBUCK), 256, 0, stream>>>(ebuf, bin_base, row_ptr, inv_deg, col);

    // --- bf16 conversions ---
    prep_kernel<<<dim3(NB_F2BF + 512), 256, 0, stream>>>(x, xb, W1, W1t, W2, W2t);

    // --- Layer 1 ---
    {
        constexpr int CPX = ((N_NODES + 31) / 32 + 3) / 4;   // 391
        agg_mean_sliced<F_IN, 2><<<dim3(8 * CPX), 256, 0, stream>>>(
            xb, row_ptr, col, inv_deg, xnb);
    }
    gemm_bt_bf16<128, true><<<dim3(784), 256, 0, stream>>>(xb, xnb, W1t, b1, h1b, N_NODES);

    // --- Layer 2 ---
    {
        constexpr int CPX = ((N_NODES + 31) / 32 + 1) / 2;   // 782
        agg_mean_sliced<F_HID, 4><<<dim3(8 * CPX), 256, 0, stream>>>(
            h1b, row_ptr, col, inv_deg, h1nb);
    }
    gemm_bt_bf16<256, false><<<dim3(784), 256, 0, stream>>>(h1b, h1nb, W2t, b2, out, N_NODES);
}